// Round 1
// baseline (71.380 us; speedup 1.0000x reference)
//
#include <hip/hip_runtime.h>
#include <math.h>

static constexpr int B   = 512;
static constexpr int NP  = 128;
static constexpr int NG  = 128;
static constexpr int TT  = 5;
static constexpr int NGI = NG * TT;  // 640 interpolated gt points

// One block per batch element. 256 threads: thread = (h, p), h in {0,1} scans
// half of the 640 candidates for pred point p. g is wave-uniform inside the
// scan loop -> LDS broadcast reads (no bank conflicts).
__global__ __launch_bounds__(256) void dm_main(
    const float* __restrict__ pred,   // [B, NP, 2]
    const float* __restrict__ gt,     // [B, NG, 2]
    double* __restrict__ partial)     // [B] per-block smooth-l1 sums
{
    __shared__ float4 sgi[NGI];       // x, y, |g|^2, pad
    __shared__ float  sgt[NG * 2];
    __shared__ float  sbest[256];
    __shared__ int    sbidx[256];
    __shared__ double sred[128];

    const int b   = blockIdx.x;
    const int tid = threadIdx.x;

    // stage gt polygon
    const float* gtb = gt + (size_t)b * NG * 2;
    for (int i = tid; i < NG * 2; i += 256) sgt[i] = gtb[i];
    __syncthreads();

    // interp[g= i*T + t] = gt[i]*step[t] + gt[i-1 mod NG]*(1-step[t])
    // (jnp.roll shift=1: roll[i] = poly[i-1]).  Match reference rounding:
    // mul, mul, add — no fma contraction.
    for (int g = tid; g < NGI; g += 256) {
        const int i  = g / TT;
        const int t  = g - i * TT;
        const float st = __fdiv_rn((float)t, (float)TT);
        const float om = __fsub_rn(1.0f, st);
        const int ip = (i == 0) ? (NG - 1) : (i - 1);
        const float x  = __fadd_rn(__fmul_rn(sgt[2*i],   st), __fmul_rn(sgt[2*ip],   om));
        const float y  = __fadd_rn(__fmul_rn(sgt[2*i+1], st), __fmul_rn(sgt[2*ip+1], om));
        const float g2 = __fadd_rn(__fmul_rn(x, x), __fmul_rn(y, y));
        sgi[g] = make_float4(x, y, g2, 0.0f);
    }
    __syncthreads();

    const int p = tid & (NP - 1);
    const int h = tid >> 7;
    const float2 pv = ((const float2*)(pred + (size_t)b * NP * 2))[p];
    const float px = pv.x, py = pv.y;
    const float p2 = __fadd_rn(__fmul_rn(px, px), __fmul_rn(py, py));

    // reference dist form: (g2 + p2) - 2*dot, dot = gx*px + gy*py.
    // strict '<' keeps the first occurrence (jnp.argmin semantics).
    float best = INFINITY;
    int   bidx = 0;
    const int g0 = h * (NGI / 2), g1 = g0 + (NGI / 2);
    for (int g = g0; g < g1; ++g) {
        const float4 gv = sgi[g];
        const float dot = __fadd_rn(__fmul_rn(gv.x, px), __fmul_rn(gv.y, py));
        const float d   = __fsub_rn(__fadd_rn(gv.z, p2), __fmul_rn(2.0f, dot));
        if (d < best) { best = d; bidx = g; }
    }
    sbest[tid] = best;
    sbidx[tid] = bidx;
    __syncthreads();

    if (h == 0) {
        const float d1 = sbest[tid + 128];
        const int   i1 = sbidx[tid + 128];
        // lower half holds smaller g indices: ties go to it (first occurrence)
        const int idx = (best <= d1) ? bidx : i1;
        const float4 m = sgi[idx];
        const float dx = fabsf(__fsub_rn(px, m.x));
        const float dy = fabsf(__fsub_rn(py, m.y));
        const float lx = (dx < 1.0f) ? __fmul_rn(0.5f, __fmul_rn(dx, dx)) : __fsub_rn(dx, 0.5f);
        const float ly = (dy < 1.0f) ? __fmul_rn(0.5f, __fmul_rn(dy, dy)) : __fsub_rn(dy, 0.5f);
        sred[p] = (double)lx + (double)ly;
    }
    __syncthreads();

    // deterministic block reduce of 128 doubles
    for (int s = 64; s > 0; s >>= 1) {
        if (tid < s) sred[tid] += sred[tid + s];
        __syncthreads();
    }
    if (tid == 0) partial[b] = sred[0];
}

__global__ __launch_bounds__(256) void dm_finalize(
    const double* __restrict__ partial, float* __restrict__ out)
{
    __shared__ double sred[256];
    const int tid = threadIdx.x;
    sred[tid] = partial[tid] + partial[tid + 256];
    __syncthreads();
    for (int s = 128; s > 0; s >>= 1) {
        if (tid < s) sred[tid] += sred[tid + s];
        __syncthreads();
    }
    if (tid == 0) out[0] = (float)(sred[0] / (double)((size_t)B * NP * 2));
}

extern "C" void kernel_launch(void* const* d_in, const int* in_sizes, int n_in,
                              void* d_out, int out_size, void* d_ws, size_t ws_size,
                              hipStream_t stream) {
    // inputs: [0] init_polys (unused by the isinit=False branch),
    //         [1] pred_poly [512,128,2] f32, [2] gt_polys [512,128,2] f32
    const float* pred = (const float*)d_in[1];
    const float* gt   = (const float*)d_in[2];
    double* partial   = (double*)d_ws;   // 512 * 8 B = 4 KiB scratch

    dm_main<<<B, 256, 0, stream>>>(pred, gt, partial);
    dm_finalize<<<1, 256, 0, stream>>>(partial, (float*)d_out);
}

// Round 2
// 67.639 us; speedup vs baseline: 1.0553x; 1.0553x over previous
//
#include <hip/hip_runtime.h>
#include <math.h>

static constexpr int B   = 512;
static constexpr int NP  = 128;
static constexpr int NG  = 128;
static constexpr int TT  = 5;
static constexpr int NGI = NG * TT;          // 640 interpolated gt points
static constexpr float INV_CNT = 1.0f / (float)(B * NP * 2);

// One block per batch. 512 threads = (h in 0..3, p in 0..127): 4 threads per
// pred point, each scans 160 of the 640 candidates. Candidate address is
// wave-uniform -> LDS broadcast b128 reads (2 float2 candidates per read).
// Argmin via packed u32 key: (bits(d) & ~1023) | g  (d >= 0, g < 1024), so
// one v_min_u32 replaces cmp+cndmask and ties resolve to the smallest g.
__global__ __launch_bounds__(512) void dm_main(
    const float* __restrict__ pred,   // [B, NP, 2]
    const float* __restrict__ gt,     // [B, NG, 2]
    float* __restrict__ partial)      // [B]
{
    __shared__ float2   sgi[NGI];     // interpolated gt points
    __shared__ float    sgt[NG * 2];
    __shared__ unsigned skey[512];
    __shared__ float    swsum[2];

    const int b   = blockIdx.x;
    const int tid = threadIdx.x;

    // stage gt polygon (1 KB): one wave, float4-coalesced
    const float* gtb = gt + (size_t)b * NG * 2;
    if (tid < 64) ((float4*)sgt)[tid] = ((const float4*)gtb)[tid];
    __syncthreads();

    // interp[g = i*T + t] = gt[i]*st + gt[(i-1) mod NG]*(1-st)
    {
        int g = tid;
        #pragma unroll
        for (int r = 0; r < 2; ++r) {
            if (g < NGI) {
                const int i  = g / TT;
                const int t  = g - i * TT;
                const float st = (float)t * 0.2f;
                const float om = 1.0f - st;
                const int ip = (i == 0) ? (NG - 1) : (i - 1);
                sgi[g] = make_float2(sgt[2*i]   * st + sgt[2*ip]   * om,
                                     sgt[2*i+1] * st + sgt[2*ip+1] * om);
            }
            g += 512;
        }
    }
    __syncthreads();

    const int p = tid & (NP - 1);
    const int h = tid >> 7;                       // 0..3
    const float2 pv = ((const float2*)(pred + (size_t)b * NP * 2))[p];
    const float px = pv.x, py = pv.y;

    unsigned k0 = 0xFFFFFFFFu, k1 = 0xFFFFFFFFu;  // two chains for ILP
    const int c0 = h * (NGI / 4);                 // 160 candidates, even start
    const float4* sgi4 = (const float4*)sgi;
    #pragma unroll 8
    for (int j = 0; j < NGI / 8; ++j) {           // 80 b128 reads = 160 cands
        const float4 c = sgi4[(c0 >> 1) + j];
        const float dx0 = px - c.x, dy0 = py - c.y;
        const float d0  = fmaf(dy0, dy0, dx0 * dx0);
        k0 = min(k0, (__float_as_uint(d0) & 0xFFFFFC00u) | (unsigned)(c0 + 2*j));
        const float dx1 = px - c.z, dy1 = py - c.w;
        const float d1  = fmaf(dy1, dy1, dx1 * dx1);
        k1 = min(k1, (__float_as_uint(d1) & 0xFFFFFC00u) | (unsigned)(c0 + 2*j + 1));
    }
    skey[tid] = min(k0, k1);
    __syncthreads();

    if (tid < 128) {                              // waves 0,1 fully active
        const unsigned k = min(min(skey[tid],       skey[tid + 128]),
                               min(skey[tid + 256], skey[tid + 384]));
        const float2 m = sgi[k & 1023u];
        const float dx = fabsf(px - m.x);
        const float dy = fabsf(py - m.y);
        const float lx = (dx < 1.0f) ? 0.5f * dx * dx : dx - 0.5f;
        const float ly = (dy < 1.0f) ? 0.5f * dy * dy : dy - 0.5f;
        float v = lx + ly;
        #pragma unroll
        for (int off = 32; off > 0; off >>= 1) v += __shfl_down(v, off);
        if ((tid & 63) == 0) swsum[tid >> 6] = v;
    }
    __syncthreads();
    if (tid == 0) partial[b] = swsum[0] + swsum[1];
}

__global__ __launch_bounds__(256) void dm_finalize(
    const float* __restrict__ partial, float* __restrict__ out)
{
    __shared__ float s[4];
    const int tid = threadIdx.x;
    float v = partial[tid] + partial[tid + 256];
    #pragma unroll
    for (int off = 32; off > 0; off >>= 1) v += __shfl_down(v, off);
    if ((tid & 63) == 0) s[tid >> 6] = v;
    __syncthreads();
    if (tid == 0) out[0] = (s[0] + s[1] + s[2] + s[3]) * INV_CNT;
}

extern "C" void kernel_launch(void* const* d_in, const int* in_sizes, int n_in,
                              void* d_out, int out_size, void* d_ws, size_t ws_size,
                              hipStream_t stream) {
    // inputs: [0] init_polys (unused), [1] pred_poly [512,128,2] f32,
    //         [2] gt_polys [512,128,2] f32
    const float* pred = (const float*)d_in[1];
    const float* gt   = (const float*)d_in[2];
    float* partial    = (float*)d_ws;   // 512 * 4 B scratch

    dm_main<<<B, 512, 0, stream>>>(pred, gt, partial);
    dm_finalize<<<1, 256, 0, stream>>>(partial, (float*)d_out);
}